// Round 13
// baseline (541.035 us; speedup 1.0000x reference)
//
#include <hip/hip_runtime.h>
#include <math.h>

typedef unsigned short u16;
typedef __attribute__((ext_vector_type(8))) short short8;
typedef __attribute__((ext_vector_type(4))) float f32x4;
typedef __attribute__((ext_vector_type(4))) unsigned short u16x4;

#define HN 16
#define KVH 8
#define DH 256
#define HID 3584
#define T_LEN 3072
#define QKV_N 8192   // H*D + 2*KV*D
#define O_N 4096     // H*D
#define WIN 1535
#define SCALING 0.0625f
#define SOFTCAP 50.0f
#define KOFF 4096    // HN*DH
#define VOFF 6144    // HN*DH + KVH*DH
#define PSTR 72
#define NJT 48       // T_LEN/64
#define M_FIX 20.0f  // fixed softmax max; valid because softcap bounds |s|<=50

__device__ __forceinline__ u16 f2bf(float f) {
  unsigned u = __float_as_uint(f);
  u += 0x7FFFu + ((u >> 16) & 1u);
  return (u16)(u >> 16);
}
__device__ __forceinline__ float bf2f(u16 b) {
  return __uint_as_float(((unsigned)b) << 16);
}

__device__ __forceinline__ void gload_lds16(const void* g, void* l) {
  __builtin_amdgcn_global_load_lds(
      (const __attribute__((address_space(1))) void*)g,
      (__attribute__((address_space(3))) void*)l, 16, 0, 0);
}

__device__ __forceinline__ f32x4 mfma_bf16(short8 a, short8 b, f32x4 c) {
  return __builtin_amdgcn_mfma_f32_16x16x32_bf16(a, b, c, 0, 0, 0);
}

#define BARX()                                  \
  do {                                          \
    __builtin_amdgcn_sched_barrier(0);          \
    __builtin_amdgcn_s_barrier();               \
    __builtin_amdgcn_sched_barrier(0);          \
  } while (0)

// ------- fused f32->bf16 convert (two buffers) + rope-table tail ----------
__global__ __launch_bounds__(256) void cvt2_kernel(const float* __restrict__ a,
                                                   u16* __restrict__ da, int nva,
                                                   const float* __restrict__ b,
                                                   u16* __restrict__ db, int nvb,
                                                   float* __restrict__ rtab) {
  const int bid = blockIdx.x;
  if (bid < 1536) {
    int idx = bid * 256 + threadIdx.x;  // < 393216 = T_LEN*128
    int d = idx & 127;
    int t = idx >> 7;
    float inv = exp2f((float)d * (-13.287712379549449f / 128.0f));  // 1e4^(-d/128)
    float ang = (float)t * inv;
    float2 cs;
    cs.x = cosf(ang);
    cs.y = sinf(ang);
    *(float2*)(rtab + (size_t)idx * 2) = cs;
  }
  int v = bid * 256 + threadIdx.x;
  const float* src;
  u16* dst;
  if (v < nva) {
    src = a + (size_t)v * 4;
    dst = da + (size_t)v * 4;
  } else if (v < nva + nvb) {
    int u = v - nva;
    src = b + (size_t)u * 4;
    dst = db + (size_t)u * 4;
  } else {
    return;
  }
  float4 x = *(const float4*)src;
  u16x4 o;
  o[0] = f2bf(x.x); o[1] = f2bf(x.y); o[2] = f2bf(x.z); o[3] = f2bf(x.w);
  *(u16x4*)dst = o;
}

// ============ GEMM1: 256 full 256x256 tiles + 256 half 128x256 jobs ========
// bids 0..255: full tiles (bm 0..7), proven 4-phase 8-phase-template body.
// bids 256..511: M-split halves of tiles bm 8..11 (j=bid-256; mhalf=j>>7;
// s=swz128(j&127)). Disjoint outputs, no atomics; rope pair thread-local.
// Half path = 2-phase variant: P0 {read B all + A01; stage (u+1).A},
// P1 {read A23; stage (u+2).B0,B1; vmcnt(4)}. Ledger: (u+1).A's buffer
// reads drained (u-1).P1; (u+2).B's buffer B-reads drained u.P0.
__global__ __launch_bounds__(512, 2) void gemm1_kernel(const u16* __restrict__ A,
                                                       const u16* __restrict__ B,
                                                       u16* __restrict__ C,
                                                       const float* __restrict__ rtab) {
  __shared__ u16 sA[2][256 * 64];
  __shared__ u16 sB[2][256 * 64];

  const int N = QKV_N, K = HID;
  const int bid = blockIdx.x;
  const int tid = threadIdx.x;
  const int lane = tid & 63, wid = tid >> 6;
  const int NT = K >> 6;  // 56
  const int srow = lane >> 3;
  const int sg = (lane & 7) ^ srow;
  const int fr = lane & 15;
  const int fh = fr & 7;
  const int gk0 = (lane >> 4) ^ fh;
  const int gk1 = ((lane >> 4) + 4) ^ fh;

  int bm, bn, row0, mhalf = 0;
  const int isFull = (bid < 256);
  if (isFull) {
    const int wg = (bid & 7) * 32 + (bid >> 3);
    bm = wg >> 5; bn = wg & 31;           // bm 0..7
    row0 = bm * 256;
  } else {
    const int j = bid - 256;
    mhalf = j >> 7;
    const int j2 = j & 127;
    const int s = (j2 & 7) * 16 + (j2 >> 3);
    bm = 8 + (s >> 5); bn = s & 31;       // bm 8..11
    row0 = bm * 256 + mhalf * 128;
  }
  const int col0 = bn * 256;
  const int wc = wid & 3;

  // stage one 128-row unit (2 gloads/thread). kinds: 0,1 = B halves; 2,3 = A
  // halves (full path); half path uses kind 2 only (its A is 128 rows).
  auto stage = [&](int tau, int kind) {
    if (tau >= NT) return;
    const int b = tau & 1;
    const u16* src;
    u16* dst;
    if (kind >= 2) {
      const int rbase = (kind - 2) * 128;
      src = A + (size_t)(row0 + rbase + wid * 8 + srow) * K + (size_t)tau * 64 + sg * 8;
      dst = &sA[b][(rbase + wid * 8) * 64];
    } else {
      const int rbase = kind * 128;
      src = B + (size_t)(col0 + rbase + wid * 8 + srow) * K + (size_t)tau * 64 + sg * 8;
      dst = &sB[b][(rbase + wid * 8) * 64];
    }
    gload_lds16(src, dst);
    gload_lds16(src + (size_t)64 * K, dst + 64 * 64);
  };

// column map: ni 0,1 -> wc*32 + ni*16; ni 2,3 -> wc*32 + 128 + (ni-2)*16
#define CMAP(ni) (wc * 32 + ((ni) & 1) * 16 + ((ni) >> 1) * 128)
#define LDB_(pB, ni, kk) (*(const short8*)&pB[(CMAP(ni) + fr) * 64 + (kk ? gk1 : gk0) * 8])
#define LDA_(pA, mrow, kk) (*(const short8*)&pA[((mrow) + fr) * 64 + (kk ? gk1 : gk0) * 8])
#define MFMA2(AF, acc0, acc1)                                            \
  __builtin_amdgcn_s_setprio(1);                                        \
  _Pragma("unroll") for (int ni = 0; ni < 4; ++ni) {                    \
    acc0[ni] = mfma_bf16(AF[0][0], bf[ni][0], acc0[ni]);                \
    acc0[ni] = mfma_bf16(AF[0][1], bf[ni][1], acc0[ni]);                \
    acc1[ni] = mfma_bf16(AF[1][0], bf[ni][0], acc1[ni]);                \
    acc1[ni] = mfma_bf16(AF[1][1], bf[ni][1], acc1[ni]);                \
  }                                                                      \
  __builtin_amdgcn_s_setprio(0);                                        \
  asm volatile("s_waitcnt lgkmcnt(0)" ::: "memory");

#define ROPE_WRITE(ACC, MROWG)                                           \
  _Pragma("unroll") for (int nh = 0; nh < 2; ++nh) {                    \
    const int dlo = wc * 32 + nh * 16 + fr;                             \
    _Pragma("unroll") for (int j = 0; j < 4; ++j) {                     \
      const int r = (MROWG) + (lane >> 4) * 4 + j;                      \
      float2 cs = *(const float2*)(rtab + ((size_t)(r << 7) + dlo) * 2);\
      float xlo = ACC[nh][j], xhi = ACC[nh + 2][j];                     \
      C[(size_t)r * N + col0 + dlo] = f2bf(xlo * cs.x - xhi * cs.y);    \
      C[(size_t)r * N + col0 + dlo + 128] = f2bf(xhi * cs.x + xlo * cs.y); \
    }                                                                    \
  }
#define PLAIN_WRITE(ACC, MROWG)                                          \
  _Pragma("unroll") for (int ni = 0; ni < 4; ++ni) {                    \
    const int r0 = (MROWG) + (lane >> 4) * 4;                           \
    const int c = col0 + CMAP(ni) + fr;                                 \
    _Pragma("unroll") for (int j = 0; j < 4; ++j)                       \
      C[(size_t)(r0 + j) * N + c] = f2bf(ACC[ni][j]);                   \
  }

  if (isFull) {
    const int wr = wid >> 2;
    f32x4 acc[8][4] = {};
    stage(0, 0); stage(0, 1); stage(0, 2); stage(0, 3);
    stage(1, 0); stage(1, 1); stage(1, 2);
    __builtin_amdgcn_sched_barrier(0);
    asm volatile("s_waitcnt vmcnt(6)" ::: "memory");
    BARX();

    for (int u = 0; u < NT; ++u) {
      const int b = u & 1;
      const u16* pA = &sA[b][0];
      const u16* pB = &sB[b][0];
      short8 bf[4][2], afA[2][2], afB[2][2];
      // ---- P0
#pragma unroll
      for (int ni = 0; ni < 4; ++ni) { bf[ni][0] = LDB_(pB, ni, 0); bf[ni][1] = LDB_(pB, ni, 1); }
      afA[0][0] = LDA_(pA, wr * 128 + 0 * 16, 0); afA[0][1] = LDA_(pA, wr * 128 + 0 * 16, 1);
      afA[1][0] = LDA_(pA, wr * 128 + 1 * 16, 0); afA[1][1] = LDA_(pA, wr * 128 + 1 * 16, 1);
      stage(u + 1, 3);
      BARX();
      MFMA2(afA, acc[0], acc[1]);
      BARX();
      // ---- P1
      afA[0][0] = LDA_(pA, wr * 128 + 2 * 16, 0); afA[0][1] = LDA_(pA, wr * 128 + 2 * 16, 1);
      afA[1][0] = LDA_(pA, wr * 128 + 3 * 16, 0); afA[1][1] = LDA_(pA, wr * 128 + 3 * 16, 1);
      stage(u + 2, 0);
      BARX();
      MFMA2(afA, acc[2], acc[3]);
      BARX();
      // ---- P2
      afA[0][0] = LDA_(pA, wr * 128 + 4 * 16, 0); afA[0][1] = LDA_(pA, wr * 128 + 4 * 16, 1);
      afA[1][0] = LDA_(pA, wr * 128 + 5 * 16, 0); afA[1][1] = LDA_(pA, wr * 128 + 5 * 16, 1);
      afB[0][0] = LDA_(pA, wr * 128 + 6 * 16, 0); afB[0][1] = LDA_(pA, wr * 128 + 6 * 16, 1);
      afB[1][0] = LDA_(pA, wr * 128 + 7 * 16, 0); afB[1][1] = LDA_(pA, wr * 128 + 7 * 16, 1);
      stage(u + 2, 1);
      BARX();
      MFMA2(afA, acc[4], acc[5]);
      BARX();
      // ---- P3
      stage(u + 2, 2);
      __builtin_amdgcn_sched_barrier(0);
      if (u + 2 < NT) {
        asm volatile("s_waitcnt vmcnt(6)" ::: "memory");
      } else {
        asm volatile("s_waitcnt vmcnt(0)" ::: "memory");
      }
      BARX();
      MFMA2(afB, acc[6], acc[7]);
      BARX();
    }
    // epilogue: rope on q,k tiles (bn<24), plain on v tiles
    if (bn < 24) {
#pragma unroll
      for (int mi = 0; mi < 8; ++mi) { ROPE_WRITE(acc[mi], row0 + wr * 128 + mi * 16); }
    } else {
#pragma unroll
      for (int mi = 0; mi < 8; ++mi) { PLAIN_WRITE(acc[mi], row0 + wr * 128 + mi * 16); }
    }
  } else {
    // ---------------- half path: 128x256, 2 phases/K-tile ----------------
    const int wr = wid >> 2;  // rows wr*64 within the 128
    f32x4 acc[4][4] = {};
    stage(0, 0); stage(0, 1); stage(0, 2);
    stage(1, 0); stage(1, 1);
    __builtin_amdgcn_sched_barrier(0);
    asm volatile("s_waitcnt vmcnt(4)" ::: "memory");
    BARX();

    for (int u = 0; u < NT; ++u) {
      const int b = u & 1;
      const u16* pA = &sA[b][0];
      const u16* pB = &sB[b][0];
      short8 bf[4][2], afA[2][2], afB[2][2];
      // ---- P0: read B all + A0,A1; stage (u+1).A
#pragma unroll
      for (int ni = 0; ni < 4; ++ni) { bf[ni][0] = LDB_(pB, ni, 0); bf[ni][1] = LDB_(pB, ni, 1); }
      afA[0][0] = LDA_(pA, wr * 64 + 0 * 16, 0); afA[0][1] = LDA_(pA, wr * 64 + 0 * 16, 1);
      afA[1][0] = LDA_(pA, wr * 64 + 1 * 16, 0); afA[1][1] = LDA_(pA, wr * 64 + 1 * 16, 1);
      stage(u + 1, 2);
      BARX();
      MFMA2(afA, acc[0], acc[1]);
      BARX();
      // ---- P1: read A2,A3; stage (u+2).B0,B1; vmcnt(4)
      afB[0][0] = LDA_(pA, wr * 64 + 2 * 16, 0); afB[0][1] = LDA_(pA, wr * 64 + 2 * 16, 1);
      afB[1][0] = LDA_(pA, wr * 64 + 3 * 16, 0); afB[1][1] = LDA_(pA, wr * 64 + 3 * 16, 1);
      stage(u + 2, 0); stage(u + 2, 1);
      __builtin_amdgcn_sched_barrier(0);
      if (u + 2 < NT) {
        asm volatile("s_waitcnt vmcnt(4)" ::: "memory");
      } else {
        asm volatile("s_waitcnt vmcnt(0)" ::: "memory");
      }
      BARX();
      MFMA2(afB, acc[2], acc[3]);
      BARX();
    }
    if (bn < 24) {
#pragma unroll
      for (int mi = 0; mi < 4; ++mi) { ROPE_WRITE(acc[mi], row0 + wr * 64 + mi * 16); }
    } else {
#pragma unroll
      for (int mi = 0; mi < 4; ++mi) { PLAIN_WRITE(acc[mi], row0 + wr * 64 + mi * 16); }
    }
  }
#undef CMAP
#undef LDB_
#undef LDA_
#undef MFMA2
#undef ROPE_WRITE
#undef PLAIN_WRITE
}

// ---------------- GEMM2: 256x256, BK=64, 8-phase (round-7 proven) ----------
__global__ __launch_bounds__(512, 2) void gemm8p(const u16* __restrict__ A,
                                                 const u16* __restrict__ B,
                                                 float* __restrict__ C,
                                                 int N, int K, int ntn, int cpx) {
  __shared__ u16 sA[2][256 * 64];
  __shared__ u16 sB[2][256 * 64];

  const int bid = blockIdx.x;
  const int tid = threadIdx.x;
  const int wg = (bid & 7) * cpx + (bid >> 3);
  const int bm = wg / ntn, bn = wg % ntn;
  const int row0 = bm * 256, col0 = bn * 256;
  const int lane = tid & 63, wid = tid >> 6;
  const int wr = wid >> 2, wc = wid & 3;
  const int NT = K >> 6;

  const int srow = lane >> 3;
  const int sg = (lane & 7) ^ srow;

  auto stage = [&](int tau, int kind) {
    if (tau >= NT) return;
    const int b = tau & 1;
    const int rbase = (kind & 1) * 128;
    const u16* src;
    u16* dst;
    if (kind >= 2) {
      src = A + (size_t)(row0 + rbase + wid * 8 + srow) * K + (size_t)tau * 64 + sg * 8;
      dst = &sA[b][(rbase + wid * 8) * 64];
    } else {
      src = B + (size_t)(col0 + rbase + wid * 8 + srow) * K + (size_t)tau * 64 + sg * 8;
      dst = &sB[b][(rbase + wid * 8) * 64];
    }
    gload_lds16(src, dst);
    gload_lds16(src + (size_t)64 * K, dst + 64 * 64);
  };

  f32x4 acc[8][4] = {};
  const int fr = lane & 15;
  const int fh = fr & 7;
  const int gk0 = (lane >> 4) ^ fh;
  const int gk1 = ((lane >> 4) + 4) ^ fh;

  stage(0, 0); stage(0, 1); stage(0, 2); stage(0, 3);
  stage(1, 0); stage(1, 1); stage(1, 2);
  __builtin_amdgcn_sched_barrier(0);
  asm volatile("s_waitcnt vmcnt(6)" ::: "memory");
  BARX();

  for (int u = 0; u < NT; ++u) {
    const int b = u & 1;
    const u16* pA = &sA[b][0];
    const u16* pB = &sB[b][0];
    short8 bf[4][2], afA[2][2], afB[2][2];

#define CMAP(ni) (wc * 32 + ((ni) & 1) * 16 + ((ni) >> 1) * 128)
#define LDB_(ni, kk) (*(const short8*)&pB[(CMAP(ni) + fr) * 64 + (kk ? gk1 : gk0) * 8])
#define LDA_(mi, kk) (*(const short8*)&pA[(wr * 128 + (mi)*16 + fr) * 64 + (kk ? gk1 : gk0) * 8])
#define MFMA2(AF, mi0)                                                   \
  __builtin_amdgcn_s_setprio(1);                                        \
  _Pragma("unroll") for (int ni = 0; ni < 4; ++ni) {                    \
    acc[mi0][ni] = mfma_bf16(AF[0][0], bf[ni][0], acc[mi0][ni]);        \
    acc[mi0][ni] = mfma_bf16(AF[0][1], bf[ni][1], acc[mi0][ni]);        \
    acc[mi0 + 1][ni] = mfma_bf16(AF[1][0], bf[ni][0], acc[mi0 + 1][ni]);\
    acc[mi0 + 1][ni] = mfma_bf16(AF[1][1], bf[ni][1], acc[mi0 + 1][ni]);\
  }                                                                      \
  __builtin_amdgcn_s_setprio(0);                                        \
  asm volatile("s_waitcnt lgkmcnt(0)" ::: "memory");

    // ---- P0
#pragma unroll
    for (int ni = 0; ni < 4; ++ni) { bf[ni][0] = LDB_(ni, 0); bf[ni][1] = LDB_(ni, 1); }
    afA[0][0] = LDA_(0, 0); afA[0][1] = LDA_(0, 1);
    afA[1][0] = LDA_(1, 0); afA[1][1] = LDA_(1, 1);
    stage(u + 1, 3);
    BARX();
    MFMA2(afA, 0);
    BARX();
    // ---- P1
    afA[0][0] = LDA_(2, 0); afA[0][1] = LDA_(2, 1);
    afA[1][0] = LDA_(3, 0); afA[1][1] = LDA_(3, 1);
    stage(u + 2, 0);
    BARX();
    MFMA2(afA, 2);
    BARX();
    // ---- P2
    afA[0][0] = LDA_(4, 0); afA[0][1] = LDA_(4, 1);
    afA[1][0] = LDA_(5, 0); afA[1][1] = LDA_(5, 1);
    afB[0][0] = LDA_(6, 0); afB[0][1] = LDA_(6, 1);
    afB[1][0] = LDA_(7, 0); afB[1][1] = LDA_(7, 1);
    stage(u + 2, 1);
    BARX();
    MFMA2(afA, 4);
    BARX();
    // ---- P3
    stage(u + 2, 2);
    __builtin_amdgcn_sched_barrier(0);
    if (u + 2 < NT) {
      asm volatile("s_waitcnt vmcnt(6)" ::: "memory");
    } else {
      asm volatile("s_waitcnt vmcnt(0)" ::: "memory");
    }
    BARX();
    MFMA2(afB, 6);
    BARX();
#undef CMAP
#undef LDB_
#undef LDA_
#undef MFMA2
  }

#pragma unroll
  for (int mi = 0; mi < 8; ++mi) {
#pragma unroll
    for (int ni = 0; ni < 4; ++ni) {
      const int r = row0 + wr * 128 + mi * 16 + (lane >> 4) * 4;
      const int c = col0 + wc * 32 + (ni & 1) * 16 + (ni >> 1) * 128 + fr;
#pragma unroll
      for (int j = 0; j < 4; ++j)
        C[(size_t)(r + j) * N + c] = acc[mi][ni][j];
    }
  }
}

// ---------------- V transpose: per (kvh, jtile) 32KB d-major swizzled image -
__global__ __launch_bounds__(256) void vtrans_kernel(const u16* __restrict__ qkv,
                                                     u16* __restrict__ vt) {
  __shared__ u16 tile[256 * 72];  // [d][t], stride 72
  const int jb = blockIdx.x * 64;
  const int kvh = blockIdx.y;
  const int tid = threadIdx.x;
  const int t = tid & 63, dc = tid >> 6;

  const u16* src = qkv + (size_t)(jb + t) * QKV_N + VOFF + kvh * DH + dc * 64;
#pragma unroll
  for (int i = 0; i < 8; ++i) {
    short8 v = *(const short8*)(src + i * 8);
    int d0 = dc * 64 + i * 8;
#pragma unroll
    for (int j = 0; j < 8; ++j) tile[(d0 + j) * 72 + t] = (u16)(short)v[j];
  }
  __syncthreads();

  u16* dst = vt + ((size_t)kvh * NJT + blockIdx.x) * 16384;
#pragma unroll
  for (int s = 0; s < 8; ++s) {
    int G = s * 256 + tid;            // granule index 0..2047
    int d = G >> 3, g = G & 7;
    short8 x = *(const short8*)&tile[d * 72 + ((g ^ (d & 7)) * 8)];
    *(short8*)(dst + G * 8) = x;
  }
}

// ---------------- flash attention, KV-split C=2, KVBLK=64, fixed-max -------
__global__ __launch_bounds__(256) void attn_kernel(const u16* __restrict__ qkv,
                                                   const u16* __restrict__ vt,
                                                   u16* __restrict__ po,
                                                   float* __restrict__ ml) {
  const int wg = blockIdx.x;
  const int kvh = wg & 7;
  const int rest = wg >> 3;
  const int qt = rest >> 2;
  const int c = (rest >> 1) & 1;
  const int h = kvh * 2 + (rest & 1);
  const int qb = qt * 64;
  const int tid = threadIdx.x, lane = tid & 63, w = tid >> 6;

  __shared__ u16 sK[64 * 256];
  __shared__ u16 sVt[64 * 256];
  __shared__ u16 sP[4][16 * PSTR];

  int jmin = qb - WIN; if (jmin < 0) jmin = 0;
  const int jt0 = jmin >> 6, jt1 = qb >> 6;
  const int nt = jt1 - jt0 + 1;
  const int half = (nt + 1) >> 1;
  const int t_beg = (c == 0) ? jt0 : jt0 + half;
  const int t_end = (c == 0) ? jt0 + half : jt1 + 1;  // exclusive

  const int qrow = qb + w * 16 + (lane & 15);
  short8 qf[8];
  {
    const u16* qp = qkv + (size_t)qrow * QKV_N + h * DH + (lane >> 4) * 8;
#pragma unroll
    for (int kc = 0; kc < 8; ++kc) qf[kc] = *(const short8*)(qp + kc * 32);
  }

  f32x4 O[16];
#pragma unroll
  for (int i = 0; i < 16; ++i) O[i] = f32x4{0.f, 0.f, 0.f, 0.f};
  float lrow[4] = {0.f, 0.f, 0.f, 0.f};

  const int dl = lane & 15;
  const int vb0 = dl * 64 + (((lane >> 4)) ^ (dl & 7)) * 8;
  const int vb1 = dl * 64 + (((lane >> 4) + 4) ^ (dl & 7)) * 8;

  for (int jt = t_beg; jt < t_end; ++jt) {
    const int jb = jt * 64;
#pragma unroll
    for (int i = 0; i < 8; ++i) {
      int rl = w * 16 + i * 2 + (lane >> 5);
      int g = (lane & 31) ^ (rl & 7);
      gload_lds16(qkv + (size_t)(jb + rl) * QKV_N + KOFF + kvh * DH + g * 8,
                  &sK[(w * 16 + i * 2) * 256]);
    }
    {
      const u16* vtile = vt + ((size_t)kvh * NJT + jt) * 16384;
#pragma unroll
      for (int s = 0; s < 8; ++s) {
        int id = w * 8 + s;
        gload_lds16(vtile + id * 512 + lane * 8, &sVt[id * 512]);
      }
    }
    __syncthreads();

    f32x4 S[4];
#pragma unroll
    for (int nf = 0; nf < 4; ++nf) S[nf] = f32x4{0.f, 0.f, 0.f, 0.f};
#pragma unroll
    for (int nf = 0; nf < 4; ++nf) {
      int krow = nf * 16 + (lane & 15);
#pragma unroll
      for (int kc = 0; kc < 8; ++kc) {
        int g = (kc * 4 + (lane >> 4)) ^ (krow & 7);
        short8 kf = *(const short8*)&sK[krow * 256 + g * 8];
        S[nf] = mfma_bf16(qf[kc], kf, S[nf]);
      }
    }

#pragma unroll
    for (int r = 0; r < 4; ++r) {
      const int irow = qb + w * 16 + (lane >> 4) * 4 + r;
      const int ql = (lane >> 4) * 4 + r;
#pragma unroll
      for (int nf = 0; nf < 4; ++nf) {
        int j = jb + nf * 16 + (lane & 15);
        float x = S[nf][r] * (SCALING / SOFTCAP);
        float e2 = __expf(-2.0f * fabsf(x));
        float th = (1.0f - e2) / (1.0f + e2);
        th = x >= 0.0f ? th : -th;
        float val = SOFTCAP * th;
        bool ok = (j <= irow) && (irow - j <= WIN);
        float p = ok ? __expf(val - M_FIX) : 0.0f;
        lrow[r] += p;
        sP[w][ql * PSTR + nf * 16 + (lane & 15)] = f2bf(p);
      }
    }

    short8 pf0 = *(const short8*)&sP[w][(lane & 15) * PSTR + (lane >> 4) * 8];
    short8 pf1 = *(const short8*)&sP[w][(lane & 15) * PSTR + 32 + (lane >> 4) * 8];
#pragma unroll
    for (int nf = 0; nf < 16; ++nf) {
      short8 vf0 = *(const short8*)&sVt[nf * 1024 + vb0];
      short8 vf1 = *(const short8*)&sVt[nf * 1024 + vb1];
      O[nf] = mfma_bf16(pf0, vf0, O[nf]);
      O[nf] = mfma_bf16(pf1, vf1, O[nf]);
    }
    __syncthreads();
  }

#pragma unroll
  for (int r = 0; r < 4; ++r) {
#pragma unroll
    for (int off = 8; off >= 1; off >>= 1) lrow[r] += __shfl_xor(lrow[r], off);
  }

#pragma unroll
  for (int nf = 0; nf < 16; ++nf) {
    int d = nf * 16 + (lane & 15);
#pragma unroll
    for (int r = 0; r < 4; ++r) {
      int trow = qb + w * 16 + (lane >> 4) * 4 + r;
      po[(((size_t)c * T_LEN + trow) * HN + h) * DH + d] = f2bf(O[nf][r]);
    }
  }
  if ((lane & 15) == 0) {
#pragma unroll
    for (int r = 0; r < 4; ++r) {
      int trow = qb + w * 16 + (lane >> 4) * 4 + r;
      size_t mi = (((size_t)c * T_LEN + trow) * HN + h) * 2;
      ml[mi] = M_FIX;
      ml[mi + 1] = lrow[r];
    }
  }
}

// ---------------- combine partials -> attnb; fused w_o f32->bf16 cvt -------
__global__ __launch_bounds__(256) void combine_kernel(const u16* __restrict__ po,
                                                      const float* __restrict__ ml,
                                                      u16* __restrict__ attnb,
                                                      const float* __restrict__ wo,
                                                      u16* __restrict__ wob) {
  const int t = blockIdx.x;
  const int h = threadIdx.x >> 4;
  const int d0 = (threadIdx.x & 15) * 16;
  const size_t row = (size_t)t * HN + h;
  const float l0 = ml[row * 2 + 1];
  const float l1 = ml[(size_t)T_LEN * HN * 2 + row * 2 + 1];
  const float inv = 1.0f / (l0 + l1);
  const size_t i0 = row * DH + d0;
  const size_t i1 = (size_t)T_LEN * HN * DH + i0;
#pragma unroll
  for (int half = 0; half < 2; ++half) {
    short8 x0 = *(const short8*)(po + i0 + half * 8);
    short8 x1 = *(const short8*)(po + i1 + half * 8);
    short8 o;
#pragma unroll
    for (int j = 0; j < 8; ++j)
      o[j] = (short)f2bf((bf2f((u16)x0[j]) + bf2f((u16)x1[j])) * inv);
    *(short8*)(attnb + i0 + half * 8) = o;
  }

  // fused w_o conversion (qkvb region is dead after attn; wob aliases it)
  const int nv = (HID * O_N) / 4;
  for (int v = blockIdx.x * 256 + threadIdx.x; v < nv; v += T_LEN * 256) {
    float4 x = *(const float4*)(wo + (size_t)v * 4);
    u16x4 o;
    o[0] = f2bf(x.x); o[1] = f2bf(x.y); o[2] = f2bf(x.z); o[3] = f2bf(x.w);
    *(u16x4*)(wob + (size_t)v * 4) = o;
  }
}

// ---------------- host launcher ----------------
extern "C" void kernel_launch(void* const* d_in, const int* in_sizes, int n_in,
                              void* d_out, int out_size, void* d_ws, size_t ws_size,
                              hipStream_t stream) {
  const float* hidden = (const float*)d_in[1];
  const float* w_qkv = (const float*)d_in[2];
  const float* w_o = (const float*)d_in[3];
  float* out = (float*)d_out;
  char* ws = (char*)d_ws;

  // Layout (peak 131,072,000 B):
  //  [0, 58,720,256):           wqkvb -> after GEMM1: PO[2] (50.3M) + ML (0.8M)
  //  [58,720,256, 80,740,352):  hb    -> after GEMM1: Vt (12.6M)
  //  [80,740,352, 131,072,000): qkvb  -> after attn:  wob (29.4M)
  //  rope table (3.1M) in d_out (written by cvt2, read by GEMM1, dead after).
  u16* wqkvb = (u16*)(ws);
  u16* po = (u16*)(ws);                        // [2][T][H][256] bf16
  float* ml = (float*)(ws + 50331648);         // [2][T][H][2] f32
  u16* attnb = (u16*)(ws);                     // aliases PO0
  u16* hb = (u16*)(ws + 58720256);
  u16* vtb = (u16*)(ws + 58720256);            // aliases hb (dead after GEMM1)
  u16* qkvb = (u16*)(ws + 80740352);
  u16* wob = (u16*)(ws + 80740352);
  float* ropetab = out;                        // d_out scratch until GEMM2

  {
    int nva = T_LEN * HID / 4;      // 2,752,512
    int nvb = QKV_N * HID / 4;      // 7,340,032
    cvt2_kernel<<<dim3((nva + nvb + 255) / 256), 256, 0, stream>>>(
        hidden, hb, nva, w_qkv, wqkvb, nvb, ropetab);
  }
  // GEMM1 (+fused rope): 256 full tiles (bm 0-7) + 256 half jobs (bm 8-11)
  gemm1_kernel<<<dim3(512), 512, 0, stream>>>(hb, wqkvb, qkvb, ropetab);
  vtrans_kernel<<<dim3(NJT, KVH), 256, 0, stream>>>(qkvb, vtb);
  attn_kernel<<<dim3(1536), 256, 0, stream>>>(qkvb, vtb, po, ml);
  combine_kernel<<<dim3(T_LEN), 256, 0, stream>>>(po, ml, attnb, w_o, wob);
  // GEMM2: 12x14 = 168 blocks (cpx=21)
  gemm8p<<<dim3(168), 512, 0, stream>>>(attnb, wob, out, HID, O_N, 14, 21);
}

// Round 14
// 533.917 us; speedup vs baseline: 1.0133x; 1.0133x over previous
//
#include <hip/hip_runtime.h>
#include <math.h>

typedef unsigned short u16;
typedef __attribute__((ext_vector_type(8))) short short8;
typedef __attribute__((ext_vector_type(4))) float f32x4;
typedef __attribute__((ext_vector_type(4))) unsigned short u16x4;

#define HN 16
#define KVH 8
#define DH 256
#define HID 3584
#define T_LEN 3072
#define QKV_N 8192   // H*D + 2*KV*D
#define O_N 4096     // H*D
#define WIN 1535
#define SCALING 0.0625f
#define SOFTCAP 50.0f
#define KOFF 4096    // HN*DH
#define VOFF 6144    // HN*DH + KVH*DH
#define PSTR 72
#define NJT 48       // T_LEN/64
#define M_FIX 20.0f  // fixed softmax max; valid because softcap bounds |s|<=50

__device__ __forceinline__ u16 f2bf(float f) {
  unsigned u = __float_as_uint(f);
  u += 0x7FFFu + ((u >> 16) & 1u);
  return (u16)(u >> 16);
}
__device__ __forceinline__ float bf2f(u16 b) {
  return __uint_as_float(((unsigned)b) << 16);
}

__device__ __forceinline__ void gload_lds16(const void* g, void* l) {
  __builtin_amdgcn_global_load_lds(
      (const __attribute__((address_space(1))) void*)g,
      (__attribute__((address_space(3))) void*)l, 16, 0, 0);
}

__device__ __forceinline__ f32x4 mfma_bf16(short8 a, short8 b, f32x4 c) {
  return __builtin_amdgcn_mfma_f32_16x16x32_bf16(a, b, c, 0, 0, 0);
}

#define BARX()                                  \
  do {                                          \
    __builtin_amdgcn_sched_barrier(0);          \
    __builtin_amdgcn_s_barrier();               \
    __builtin_amdgcn_sched_barrier(0);          \
  } while (0)

// ---------------- fused f32 -> bf16 convert for two buffers ----------------
__global__ __launch_bounds__(256) void cvt2_kernel(const float* __restrict__ a,
                                                   u16* __restrict__ da, int nva,
                                                   const float* __restrict__ b,
                                                   u16* __restrict__ db, int nvb) {
  int v = blockIdx.x * 256 + threadIdx.x;
  const float* src;
  u16* dst;
  if (v < nva) {
    src = a + (size_t)v * 4;
    dst = da + (size_t)v * 4;
  } else if (v < nva + nvb) {
    int u = v - nva;
    src = b + (size_t)u * 4;
    dst = db + (size_t)u * 4;
  } else {
    return;
  }
  float4 x = *(const float4*)src;
  u16x4 o;
  o[0] = f2bf(x.x); o[1] = f2bf(x.y); o[2] = f2bf(x.z); o[3] = f2bf(x.w);
  *(u16x4*)dst = o;
}

// ---------------- GEMM 256x256, BK=64, 8-phase counted-vmcnt (round-7 proven)
// Blocks >= gemmBlocks are RIDERS: they compute the rope cos/sin table into
// rtab and exit. Riders fill the idle CU slots of GEMM1's 1.5-pass schedule
// (384 tiles + 128 riders = 512 = exactly 2 rounds over 256 CUs).
template <int OUT_BF16>
__global__ __launch_bounds__(512, 2) void gemm8p(const u16* __restrict__ A,
                                                 const u16* __restrict__ B,
                                                 void* __restrict__ Cv,
                                                 int N, int K, int ntn, int cpx,
                                                 int gemmBlocks,
                                                 float* __restrict__ rtab) {
  __shared__ u16 sA[2][256 * 64];
  __shared__ u16 sB[2][256 * 64];

  const int bid = blockIdx.x;
  const int tid = threadIdx.x;

  if (bid >= gemmBlocks) {
    // rider: rope table tab[t][d] = {cos,sin}(t * 10000^(-d/128))
    const int rb = bid - gemmBlocks;
    for (int idx = rb * 512 + tid; idx < T_LEN * 128; idx += 128 * 512) {
      int d = idx & 127;
      int t = idx >> 7;
      float inv = exp2f((float)d * (-13.287712379549449f / 128.0f));
      float ang = (float)t * inv;
      float2 cs;
      cs.x = cosf(ang);
      cs.y = sinf(ang);
      *(float2*)(rtab + (size_t)idx * 2) = cs;
    }
    return;
  }

  const int wg = (bid & 7) * cpx + (bid >> 3);  // XCD swizzle (nwg%8==0)
  const int bm = wg / ntn, bn = wg % ntn;
  const int row0 = bm * 256, col0 = bn * 256;
  const int lane = tid & 63, wid = tid >> 6;
  const int wr = wid >> 2, wc = wid & 3;
  const int NT = K >> 6;

  const int srow = lane >> 3;
  const int sg = (lane & 7) ^ srow;

  auto stage = [&](int tau, int kind) {
    if (tau >= NT) return;
    const int b = tau & 1;
    const int rbase = (kind & 1) * 128;
    const u16* src;
    u16* dst;
    if (kind >= 2) {
      src = A + (size_t)(row0 + rbase + wid * 8 + srow) * K + (size_t)tau * 64 + sg * 8;
      dst = &sA[b][(rbase + wid * 8) * 64];
    } else {
      src = B + (size_t)(col0 + rbase + wid * 8 + srow) * K + (size_t)tau * 64 + sg * 8;
      dst = &sB[b][(rbase + wid * 8) * 64];
    }
    gload_lds16(src, dst);
    gload_lds16(src + (size_t)64 * K, dst + 64 * 64);
  };

  f32x4 acc[8][4] = {};
  const int fr = lane & 15;
  const int fh = fr & 7;
  const int gk0 = (lane >> 4) ^ fh;
  const int gk1 = ((lane >> 4) + 4) ^ fh;

  stage(0, 0); stage(0, 1); stage(0, 2); stage(0, 3);
  stage(1, 0); stage(1, 1); stage(1, 2);
  __builtin_amdgcn_sched_barrier(0);
  asm volatile("s_waitcnt vmcnt(6)" ::: "memory");
  BARX();

  for (int u = 0; u < NT; ++u) {
    const int b = u & 1;
    const u16* pA = &sA[b][0];
    const u16* pB = &sB[b][0];
    short8 bf[4][2], afA[2][2], afB[2][2];

#define LDB_(ni, kk) (*(const short8*)&pB[(wc * 64 + (ni)*16 + fr) * 64 + (kk ? gk1 : gk0) * 8])
#define LDA_(mi, kk) (*(const short8*)&pA[(wr * 128 + (mi)*16 + fr) * 64 + (kk ? gk1 : gk0) * 8])
#define MFMA2(AF, mi0)                                                   \
  __builtin_amdgcn_s_setprio(1);                                        \
  _Pragma("unroll") for (int ni = 0; ni < 4; ++ni) {                    \
    acc[mi0][ni] = mfma_bf16(AF[0][0], bf[ni][0], acc[mi0][ni]);        \
    acc[mi0][ni] = mfma_bf16(AF[0][1], bf[ni][1], acc[mi0][ni]);        \
    acc[mi0 + 1][ni] = mfma_bf16(AF[1][0], bf[ni][0], acc[mi0 + 1][ni]);\
    acc[mi0 + 1][ni] = mfma_bf16(AF[1][1], bf[ni][1], acc[mi0 + 1][ni]);\
  }                                                                      \
  __builtin_amdgcn_s_setprio(0);                                        \
  asm volatile("s_waitcnt lgkmcnt(0)" ::: "memory");

    // ---- P0
#pragma unroll
    for (int ni = 0; ni < 4; ++ni) { bf[ni][0] = LDB_(ni, 0); bf[ni][1] = LDB_(ni, 1); }
    afA[0][0] = LDA_(0, 0); afA[0][1] = LDA_(0, 1);
    afA[1][0] = LDA_(1, 0); afA[1][1] = LDA_(1, 1);
    stage(u + 1, 3);
    BARX();
    MFMA2(afA, 0);
    BARX();
    // ---- P1
    afA[0][0] = LDA_(2, 0); afA[0][1] = LDA_(2, 1);
    afA[1][0] = LDA_(3, 0); afA[1][1] = LDA_(3, 1);
    stage(u + 2, 0);
    BARX();
    MFMA2(afA, 2);
    BARX();
    // ---- P2
    afA[0][0] = LDA_(4, 0); afA[0][1] = LDA_(4, 1);
    afA[1][0] = LDA_(5, 0); afA[1][1] = LDA_(5, 1);
    afB[0][0] = LDA_(6, 0); afB[0][1] = LDA_(6, 1);
    afB[1][0] = LDA_(7, 0); afB[1][1] = LDA_(7, 1);
    stage(u + 2, 1);
    BARX();
    MFMA2(afA, 4);
    BARX();
    // ---- P3
    stage(u + 2, 2);
    __builtin_amdgcn_sched_barrier(0);
    if (u + 2 < NT) {
      asm volatile("s_waitcnt vmcnt(6)" ::: "memory");
    } else {
      asm volatile("s_waitcnt vmcnt(0)" ::: "memory");
    }
    BARX();
    MFMA2(afB, 6);
    BARX();
#undef LDB_
#undef LDA_
#undef MFMA2
  }

#pragma unroll
  for (int mi = 0; mi < 8; ++mi) {
#pragma unroll
    for (int ni = 0; ni < 4; ++ni) {
      const int r = row0 + wr * 128 + mi * 16 + (lane >> 4) * 4;
      const int c = col0 + wc * 64 + ni * 16 + (lane & 15);
#pragma unroll
      for (int j = 0; j < 4; ++j) {
        float v = acc[mi][ni][j];
        if (OUT_BF16)
          ((u16*)Cv)[(size_t)(r + j) * N + c] = f2bf(v);
        else
          ((float*)Cv)[(size_t)(r + j) * N + c] = v;
      }
    }
  }
}

// ---------------- RoPE (NeoX) in-place on q,k of qkv (bf16), table-based ---
__global__ __launch_bounds__(256) void rope_kernel(u16* __restrict__ qkv,
                                                   const float* __restrict__ tab) {
  int idx = blockIdx.x * 256 + threadIdx.x;  // T * 24 * 128
  int d = idx & 127;
  int hh = (idx >> 7) % 24;
  int t = idx / (24 * 128);
  if (t >= T_LEN) return;
  size_t base = (size_t)t * QKV_N + (hh < HN ? hh * DH : HN * DH + (hh - HN) * DH);
  float2 cs = *(const float2*)(tab + ((size_t)(t << 7) + d) * 2);
  float x1 = bf2f(qkv[base + d]);
  float x2 = bf2f(qkv[base + d + 128]);
  qkv[base + d] = f2bf(x1 * cs.x - x2 * cs.y);
  qkv[base + d + 128] = f2bf(x2 * cs.x + x1 * cs.y);
}

// ---------------- V transpose: per (kvh, jtile) 32KB d-major swizzled image -
__global__ __launch_bounds__(256) void vtrans_kernel(const u16* __restrict__ qkv,
                                                     u16* __restrict__ vt) {
  __shared__ u16 tile[256 * 72];  // [d][t], stride 72
  const int jb = blockIdx.x * 64;
  const int kvh = blockIdx.y;
  const int tid = threadIdx.x;
  const int t = tid & 63, dc = tid >> 6;

  const u16* src = qkv + (size_t)(jb + t) * QKV_N + VOFF + kvh * DH + dc * 64;
#pragma unroll
  for (int i = 0; i < 8; ++i) {
    short8 v = *(const short8*)(src + i * 8);
    int d0 = dc * 64 + i * 8;
#pragma unroll
    for (int j = 0; j < 8; ++j) tile[(d0 + j) * 72 + t] = (u16)(short)v[j];
  }
  __syncthreads();

  u16* dst = vt + ((size_t)kvh * NJT + blockIdx.x) * 16384;
#pragma unroll
  for (int s = 0; s < 8; ++s) {
    int G = s * 256 + tid;            // granule index 0..2047
    int d = G >> 3, g = G & 7;
    short8 x = *(const short8*)&tile[d * 72 + ((g ^ (d & 7)) * 8)];
    *(short8*)(dst + G * 8) = x;
  }
}

// ---------------- flash attention, KV-split C=2, KVBLK=64, fixed-max -------
__global__ __launch_bounds__(256) void attn_kernel(const u16* __restrict__ qkv,
                                                   const u16* __restrict__ vt,
                                                   u16* __restrict__ po,
                                                   float* __restrict__ ml) {
  const int wg = blockIdx.x;
  const int kvh = wg & 7;
  const int rest = wg >> 3;
  const int qt = rest >> 2;
  const int c = (rest >> 1) & 1;
  const int h = kvh * 2 + (rest & 1);
  const int qb = qt * 64;
  const int tid = threadIdx.x, lane = tid & 63, w = tid >> 6;

  __shared__ u16 sK[64 * 256];
  __shared__ u16 sVt[64 * 256];
  __shared__ u16 sP[4][16 * PSTR];

  int jmin = qb - WIN; if (jmin < 0) jmin = 0;
  const int jt0 = jmin >> 6, jt1 = qb >> 6;
  const int nt = jt1 - jt0 + 1;
  const int half = (nt + 1) >> 1;
  const int t_beg = (c == 0) ? jt0 : jt0 + half;
  const int t_end = (c == 0) ? jt0 + half : jt1 + 1;  // exclusive

  const int qrow = qb + w * 16 + (lane & 15);
  short8 qf[8];
  {
    const u16* qp = qkv + (size_t)qrow * QKV_N + h * DH + (lane >> 4) * 8;
#pragma unroll
    for (int kc = 0; kc < 8; ++kc) qf[kc] = *(const short8*)(qp + kc * 32);
  }

  f32x4 O[16];
#pragma unroll
  for (int i = 0; i < 16; ++i) O[i] = f32x4{0.f, 0.f, 0.f, 0.f};
  float lrow[4] = {0.f, 0.f, 0.f, 0.f};

  const int dl = lane & 15;
  const int vb0 = dl * 64 + (((lane >> 4)) ^ (dl & 7)) * 8;
  const int vb1 = dl * 64 + (((lane >> 4) + 4) ^ (dl & 7)) * 8;

  for (int jt = t_beg; jt < t_end; ++jt) {
    const int jb = jt * 64;
#pragma unroll
    for (int i = 0; i < 8; ++i) {
      int rl = w * 16 + i * 2 + (lane >> 5);
      int g = (lane & 31) ^ (rl & 7);
      gload_lds16(qkv + (size_t)(jb + rl) * QKV_N + KOFF + kvh * DH + g * 8,
                  &sK[(w * 16 + i * 2) * 256]);
    }
    {
      const u16* vtile = vt + ((size_t)kvh * NJT + jt) * 16384;
#pragma unroll
      for (int s = 0; s < 8; ++s) {
        int id = w * 8 + s;
        gload_lds16(vtile + id * 512 + lane * 8, &sVt[id * 512]);
      }
    }
    __syncthreads();

    f32x4 S[4];
#pragma unroll
    for (int nf = 0; nf < 4; ++nf) S[nf] = f32x4{0.f, 0.f, 0.f, 0.f};
#pragma unroll
    for (int nf = 0; nf < 4; ++nf) {
      int krow = nf * 16 + (lane & 15);
#pragma unroll
      for (int kc = 0; kc < 8; ++kc) {
        int g = (kc * 4 + (lane >> 4)) ^ (krow & 7);
        short8 kf = *(const short8*)&sK[krow * 256 + g * 8];
        S[nf] = mfma_bf16(qf[kc], kf, S[nf]);
      }
    }

#pragma unroll
    for (int r = 0; r < 4; ++r) {
      const int irow = qb + w * 16 + (lane >> 4) * 4 + r;
      const int ql = (lane >> 4) * 4 + r;
#pragma unroll
      for (int nf = 0; nf < 4; ++nf) {
        int j = jb + nf * 16 + (lane & 15);
        float x = S[nf][r] * (SCALING / SOFTCAP);
        float e2 = __expf(-2.0f * fabsf(x));
        float th = (1.0f - e2) / (1.0f + e2);
        th = x >= 0.0f ? th : -th;
        float val = SOFTCAP * th;
        bool ok = (j <= irow) && (irow - j <= WIN);
        float p = ok ? __expf(val - M_FIX) : 0.0f;
        lrow[r] += p;
        sP[w][ql * PSTR + nf * 16 + (lane & 15)] = f2bf(p);
      }
    }

    short8 pf0 = *(const short8*)&sP[w][(lane & 15) * PSTR + (lane >> 4) * 8];
    short8 pf1 = *(const short8*)&sP[w][(lane & 15) * PSTR + 32 + (lane >> 4) * 8];
#pragma unroll
    for (int nf = 0; nf < 16; ++nf) {
      short8 vf0 = *(const short8*)&sVt[nf * 1024 + vb0];
      short8 vf1 = *(const short8*)&sVt[nf * 1024 + vb1];
      O[nf] = mfma_bf16(pf0, vf0, O[nf]);
      O[nf] = mfma_bf16(pf1, vf1, O[nf]);
    }
    __syncthreads();
  }

#pragma unroll
  for (int r = 0; r < 4; ++r) {
#pragma unroll
    for (int off = 8; off >= 1; off >>= 1) lrow[r] += __shfl_xor(lrow[r], off);
  }

#pragma unroll
  for (int nf = 0; nf < 16; ++nf) {
    int d = nf * 16 + (lane & 15);
#pragma unroll
    for (int r = 0; r < 4; ++r) {
      int trow = qb + w * 16 + (lane >> 4) * 4 + r;
      po[(((size_t)c * T_LEN + trow) * HN + h) * DH + d] = f2bf(O[nf][r]);
    }
  }
  if ((lane & 15) == 0) {
#pragma unroll
    for (int r = 0; r < 4; ++r) {
      int trow = qb + w * 16 + (lane >> 4) * 4 + r;
      size_t mi = (((size_t)c * T_LEN + trow) * HN + h) * 2;
      ml[mi] = M_FIX;
      ml[mi + 1] = lrow[r];
    }
  }
}

// ---------------- combine partials -> attnb; fused w_o f32->bf16 cvt -------
__global__ __launch_bounds__(256) void combine_kernel(const u16* __restrict__ po,
                                                      const float* __restrict__ ml,
                                                      u16* __restrict__ attnb,
                                                      const float* __restrict__ wo,
                                                      u16* __restrict__ wob) {
  const int t = blockIdx.x;
  const int h = threadIdx.x >> 4;
  const int d0 = (threadIdx.x & 15) * 16;
  const size_t row = (size_t)t * HN + h;
  const float l0 = ml[row * 2 + 1];
  const float l1 = ml[(size_t)T_LEN * HN * 2 + row * 2 + 1];
  const float inv = 1.0f / (l0 + l1);
  const size_t i0 = row * DH + d0;
  const size_t i1 = (size_t)T_LEN * HN * DH + i0;
#pragma unroll
  for (int half = 0; half < 2; ++half) {
    short8 x0 = *(const short8*)(po + i0 + half * 8);
    short8 x1 = *(const short8*)(po + i1 + half * 8);
    short8 o;
#pragma unroll
    for (int j = 0; j < 8; ++j)
      o[j] = (short)f2bf((bf2f((u16)x0[j]) + bf2f((u16)x1[j])) * inv);
    *(short8*)(attnb + i0 + half * 8) = o;
  }

  // fused w_o conversion (qkvb region is dead after attn; wob aliases it)
  const int nv = (HID * O_N) / 4;
  for (int v = blockIdx.x * 256 + threadIdx.x; v < nv; v += T_LEN * 256) {
    float4 x = *(const float4*)(wo + (size_t)v * 4);
    u16x4 o;
    o[0] = f2bf(x.x); o[1] = f2bf(x.y); o[2] = f2bf(x.z); o[3] = f2bf(x.w);
    *(u16x4*)(wob + (size_t)v * 4) = o;
  }
}

// ---------------- host launcher ----------------
extern "C" void kernel_launch(void* const* d_in, const int* in_sizes, int n_in,
                              void* d_out, int out_size, void* d_ws, size_t ws_size,
                              hipStream_t stream) {
  const float* hidden = (const float*)d_in[1];
  const float* w_qkv = (const float*)d_in[2];
  const float* w_o = (const float*)d_in[3];
  float* out = (float*)d_out;
  char* ws = (char*)d_ws;

  // Layout (peak 131,072,000 B):
  //  [0, 58,720,256):           wqkvb -> after GEMM1: PO[2] (50.3M) + ML (0.8M)
  //  [58,720,256, 80,740,352):  hb    -> after GEMM1: Vt (12.6M)
  //  [80,740,352, 131,072,000): qkvb  -> after attn:  wob (29.4M)
  //  rope table (3.1M) lives in d_out until GEMM2 overwrites it.
  u16* wqkvb = (u16*)(ws);
  u16* po = (u16*)(ws);                        // [2][T][H][256] bf16
  float* ml = (float*)(ws + 50331648);         // [2][T][H][2] f32
  u16* attnb = (u16*)(ws);                     // aliases PO0
  u16* hb = (u16*)(ws + 58720256);
  u16* vtb = (u16*)(ws + 58720256);            // aliases hb (dead after GEMM1)
  u16* qkvb = (u16*)(ws + 80740352);
  u16* wob = (u16*)(ws + 80740352);
  float* ropetab = out;                        // d_out scratch until GEMM2

  {
    // fused: hidden (11,010,048 el) + w_qkv (29,360,128 el) f32->bf16
    int nva = T_LEN * HID / 4;      // 2,752,512
    int nvb = QKV_N * HID / 4;      // 7,340,032
    cvt2_kernel<<<dim3((nva + nvb + 255) / 256), 256, 0, stream>>>(
        hidden, hb, nva, w_qkv, wqkvb, nvb);
  }
  // GEMM1: M=3072 N=8192 K=3584 -> 384 tiles + 128 rope-table riders = 512
  gemm8p<1><<<dim3(512), 512, 0, stream>>>(hb, wqkvb, qkvb, QKV_N, HID, 32, 48,
                                           384, ropetab);
  {
    int n = T_LEN * 24 * 128;
    rope_kernel<<<dim3(n / 256), 256, 0, stream>>>(qkvb, ropetab);
  }
  vtrans_kernel<<<dim3(NJT, KVH), 256, 0, stream>>>(qkvb, vtb);
  attn_kernel<<<dim3(1536), 256, 0, stream>>>(qkvb, vtb, po, ml);
  combine_kernel<<<dim3(T_LEN), 256, 0, stream>>>(po, ml, attnb, w_o, wob);
  // GEMM2: M=3072 N=3584 K=4096 -> 12x14 = 168 blocks (cpx=21), no riders
  gemm8p<0><<<dim3(168), 512, 0, stream>>>(attnb, wob, out, HID, O_N, 14, 21,
                                           168, nullptr);
}